// Round 2
// 1921.823 us; speedup vs baseline: 17.9417x; 17.9417x over previous
//
#include <hip/hip_runtime.h>

// quadjetResNetBlock via fp16 MFMA.
// Per (g,l): out[n,o] = sum_{k<768} A[n,k] * B[k,o] + b[o]
//   K-order: k=2c -> x[n,c,2g], k=2c+1 -> x[n,c,2g+1], k=512+c -> q_cur[n,c]
// Weights pre-converted to fp16 LDS-image tiles in d_ws by prep_w.
// Block = 64 rows, 4 waves (each 64 rows x 64 out-cols, 4x4 16x16x32 tiles).
// A panel (64x768 fp16, 96KB) + W double-buffer (2x16KB) = 128KB LDS
// (same footprint as the verified 8-phase template).

#define NR   65536
#define CH   256
#define MB   64          // rows per block
#define KT   32          // K per tile (one MFMA K-step)
#define NKT  24          // 768/KT
#define AROW 768         // halves per A row

typedef _Float16 f16;
typedef _Float16 f16x2 __attribute__((ext_vector_type(2)));
typedef _Float16 f16x8 __attribute__((ext_vector_type(8)));
typedef float    f32x4 __attribute__((ext_vector_type(4)));

// ---- prep: W[o][c][3] fp32 -> fp16 tile images, layout [l][kt][kq][o][8]
// B-fragment reads become conflict-free: 16 lanes -> 16 distinct 16B slots.
__global__ __launch_bounds__(256)
void prep_w(const float* __restrict__ W1, const float* __restrict__ W2,
            const float* __restrict__ W3, f16* __restrict__ ws)
{
    const int bid = blockIdx.x;            // l*NKT + kt
    const int l = bid / NKT, kt = bid % NKT;
    const float* W = (l == 0) ? W1 : (l == 1) ? W2 : W3;
    const int o = threadIdx.x;
    f16* img = ws + (size_t)bid * (CH * KT);
    #pragma unroll
    for (int ks = 0; ks < KT; ++ks) {
        const int kg = kt * KT + ks;
        int c, kk;
        if (kg < 512) { c = kg >> 1;  kk = kg & 1; }
        else          { c = kg - 512; kk = 2; }
        const float w = W[((size_t)o * CH + c) * 3 + kk];
        img[((ks >> 3) << 11) + (o << 3) + (ks & 7)] = (f16)w;
    }
}

__device__ __forceinline__ void gld_lds16(const void* g, void* l) {
    __builtin_amdgcn_global_load_lds(
        (const __attribute__((address_space(1))) unsigned int*)g,
        (__attribute__((address_space(3))) unsigned int*)l, 16, 0, 0);
}

__global__ __launch_bounds__(256, 1)
void qjrb_mfma(const float* __restrict__ x, const float* __restrict__ q,
               const f16* __restrict__ wsW,
               const float* __restrict__ b1, const float* __restrict__ b2,
               const float* __restrict__ b3, float* __restrict__ out)
{
    // A: [m][k], fp16, 16B-granule-swizzled: granule_idx ^= (m&7)
    __shared__ __align__(16) f16 A[MB * AROW];        // 96 KiB
    __shared__ __align__(16) f16 Wb[2][CH * KT];      // 2 x 16 KiB

    const int tid = threadIdx.x;
    const int n0  = blockIdx.x * MB;
    const int lan = tid & 63;
    const int wv  = tid >> 6;          // wave id: out-col range wv*64
    const int lr  = lan & 15;          // A row-in-tile / B,D col-in-tile
    const int lq  = lan >> 4;          // k-granule quarter / D row-quad

    for (int g = 0; g < 3; ++g) {
        // prologue: stage layer-0 tile-0 into Wb[0] (overlaps A staging)
        {
            const char* src = (const char*)wsW;      // (l=0, kt=0)
            char* dst = (char*)&Wb[0][0];
            #pragma unroll
            for (int i = 0; i < 4; ++i)
                gld_lds16(src + tid * 16 + i * 4096, dst + tid * 16 + i * 4096);
        }
        // ---- stage A: x cols (2g,2g+1) at k=2c{,+1}; q col g at k=512+c
        {
            const int c = tid;
            const float* xp = x + ((size_t)n0 * CH + c) * 6 + 2 * g;
            const float* qp = q + ((size_t)n0 * CH + c) * 3 + g;
            #pragma unroll 4
            for (int r = 0; r < MB; ++r) {
                const float2 xx = *(const float2*)(xp + (size_t)r * CH * 6);
                const float  qq = qp[(size_t)r * CH * 3];
                const int sw = r & 7;
                f16x2 hx = { (f16)xx.x, (f16)xx.y };
                *(f16x2*)&A[r * AROW + (((c >> 2) ^ sw) << 3) + ((c & 3) << 1)] = hx;
                A[r * AROW + ((64 + ((c >> 3) ^ sw)) << 3) + (c & 7)] = (f16)qq;
            }
        }

        for (int l = 0; l < 3; ++l) {
            const float* bl = (l == 0) ? b1 : (l == 1) ? b2 : b3;
            f32x4 acc[4][4];
            #pragma unroll
            for (int nt = 0; nt < 4; ++nt) {
                const float bv = bl[wv * 64 + nt * 16 + lr];
                #pragma unroll
                for (int mt = 0; mt < 4; ++mt)
                    acc[mt][nt] = (f32x4){bv, bv, bv, bv};
            }
            __syncthreads();   // A staged + W tile0 landed (barrier drains vmcnt)

            int cur = 0;
            for (int kt = 0; kt < NKT; ++kt) {
                // 2-phase: issue next-tile stage first (next layer's tile0 at kt==23)
                if (kt < NKT - 1 || l < 2) {
                    const int nl  = (kt < NKT - 1) ? l : l + 1;
                    const int nkt = (kt < NKT - 1) ? kt + 1 : 0;
                    const char* src = (const char*)wsW + ((size_t)nl * NKT + nkt) * 16384;
                    char* dst = (char*)&Wb[cur ^ 1][0];
                    #pragma unroll
                    for (int i = 0; i < 4; ++i)
                        gld_lds16(src + tid * 16 + i * 4096, dst + tid * 16 + i * 4096);
                }
                f16x8 a[4], b[4];
                #pragma unroll
                for (int mt = 0; mt < 4; ++mt) {
                    const int m = mt * 16 + lr;
                    a[mt] = *(const f16x8*)&A[m * AROW + ((((kt << 2) + lq) ^ (lr & 7)) << 3)];
                }
                #pragma unroll
                for (int nt = 0; nt < 4; ++nt) {
                    const int o = wv * 64 + nt * 16 + lr;
                    b[nt] = *(const f16x8*)&Wb[cur][(lq << 11) + (o << 3)];
                }
                #pragma unroll
                for (int mt = 0; mt < 4; ++mt)
                    #pragma unroll
                    for (int nt = 0; nt < 4; ++nt)
                        acc[mt][nt] = __builtin_amdgcn_mfma_f32_16x16x32_f16(
                            a[mt], b[nt], acc[mt][nt], 0, 0, 0);
                __syncthreads();   // drains vmcnt (next tile landed); swap buffers
                cur ^= 1;
            }

            if (l < 2) {
                // q_cur <- relu(acc) back into A's q region (k = 512+o)
                #pragma unroll
                for (int mt = 0; mt < 4; ++mt) {
                    #pragma unroll
                    for (int i = 0; i < 4; ++i) {
                        const int m = mt * 16 + lq * 4 + i;
                        const int sw = m & 7;
                        #pragma unroll
                        for (int nt = 0; nt < 4; ++nt) {
                            const int o = wv * 64 + nt * 16 + lr;
                            A[m * AROW + ((64 + ((o >> 3) ^ sw)) << 3) + (o & 7)] =
                                (f16)fmaxf(acc[mt][nt][i], 0.f);
                        }
                    }
                }
                // next layer's top __syncthreads() publishes the q-writes
            } else {
                // epilogue: relu(acc + q_orig) -> out[n][o][g]
                #pragma unroll
                for (int mt = 0; mt < 4; ++mt) {
                    #pragma unroll
                    for (int i = 0; i < 4; ++i) {
                        const int m = mt * 16 + lq * 4 + i;
                        #pragma unroll
                        for (int nt = 0; nt < 4; ++nt) {
                            const int o = wv * 64 + nt * 16 + lr;
                            const size_t idx = (((size_t)(n0 + m)) * CH + o) * 3 + g;
                            out[idx] = fmaxf(acc[mt][nt][i] + q[idx], 0.f);
                        }
                    }
                }
            }
        }
        __syncthreads();  // all waves done with A/Wb before next-g restage
    }
}

extern "C" void kernel_launch(void* const* d_in, const int* in_sizes, int n_in,
                              void* d_out, int out_size, void* d_ws, size_t ws_size,
                              hipStream_t stream)
{
    const float* x  = (const float*)d_in[0];
    const float* q  = (const float*)d_in[1];
    const float* W1 = (const float*)d_in[2];
    const float* b1 = (const float*)d_in[3];
    const float* W2 = (const float*)d_in[4];
    const float* b2 = (const float*)d_in[5];
    const float* W3 = (const float*)d_in[6];
    const float* b3 = (const float*)d_in[7];

    if (ws_size < (size_t)3 * NKT * 16384) return;  // need 1.13 MiB for fp16 weights
    f16* ws = (f16*)d_ws;

    hipLaunchKernelGGL(prep_w, dim3(3 * NKT), dim3(256), 0, stream, W1, W2, W3, ws);
    hipLaunchKernelGGL(qjrb_mfma, dim3(NR / MB), dim3(256), 0, stream,
                       x, q, ws, b1, b2, b3, (float*)d_out);
}

// Round 3
// 1875.080 us; speedup vs baseline: 18.3889x; 1.0249x over previous
//
#include <hip/hip_runtime.h>

// quadjetResNetBlock via fp16 MFMA, v3.
// Per (g,l): out[n,o] = sum_{k<768} A[n,k] * B[k,o] + b[o]
//   K-order: k=2c -> x[n,c,2g], k=2c+1 -> x[n,c,2g+1], k=512+c -> q_cur[n,c]
// v3 changes vs v2 (1455 us, MfmaUtil 6.5%, occupancy 1 wave/SIMD):
//  - W fragments loaded DIRECTLY to registers from prepacked image (L2-hot),
//    1-deep prefetch -> no LDS W buffer, NO barriers in the K-loop
//    (A is read-only within a layer; 18 barriers/block total vs 216+).
//  - 512-thread blocks, 8 waves (2 row-halves x 4 col-quarters) -> 2 waves/SIMD.
//  - Epilogue fused across all 3 groups: three layer-3 accumulators held in
//    registers; single pass writes full 12B/(n,o) segments (kills 3.4x write
//    amplification) and reads residual q once.
// LDS: A panel only, 64 x 768 fp16 = 96 KiB.

#define NR   65536
#define CH   256
#define MB   64
#define NKT  24          // 768 / 32

typedef _Float16 f16;
typedef _Float16 f16x2 __attribute__((ext_vector_type(2)));
typedef _Float16 f16x8 __attribute__((ext_vector_type(8)));
typedef float    f32x4 __attribute__((ext_vector_type(4)));

// ---- prep: W[o][c][3] fp32 -> fp16 tile images, layout [l][kt][kq][o][8]
// halves index within tile: kq*2048 + o*8 + j ; tile stride 8192 halves.
__global__ __launch_bounds__(256)
void prep_w(const float* __restrict__ W1, const float* __restrict__ W2,
            const float* __restrict__ W3, f16* __restrict__ ws)
{
    const int bid = blockIdx.x;            // l*NKT + kt
    const int l = bid / NKT, kt = bid % NKT;
    const float* W = (l == 0) ? W1 : (l == 1) ? W2 : W3;
    const int o = threadIdx.x;
    f16* img = ws + (size_t)bid * 8192;
    #pragma unroll
    for (int ks = 0; ks < 32; ++ks) {
        const int kg = kt * 32 + ks;
        int c, kk;
        if (kg < 512) { c = kg >> 1;  kk = kg & 1; }
        else          { c = kg - 512; kk = 2; }
        const float w = W[((size_t)o * CH + c) * 3 + kk];
        img[((ks >> 3) << 11) + (o << 3) + (ks & 7)] = (f16)w;
    }
}

// K-loop over 24 tiles; W frags prefetched 1 deep into registers; no barriers.
#define KLOOP(WL, ACC0, ACC1)                                                  \
  {                                                                            \
    f16x8 wcur[4], wnxt[4];                                                    \
    _Pragma("unroll")                                                          \
    for (int nt = 0; nt < 4; ++nt)                                             \
        wcur[nt] = *(const f16x8*)((WL) + wboff + nt * 128);                   \
    _Pragma("unroll")                                                          \
    for (int kt = 0; kt < NKT; ++kt) {                                         \
        if (kt < NKT - 1) {                                                    \
            _Pragma("unroll")                                                  \
            for (int nt = 0; nt < 4; ++nt)                                     \
                wnxt[nt] = *(const f16x8*)((WL) + (kt + 1) * 8192 + wboff + nt * 128); \
        }                                                                      \
        const int ak = abase + ((((kt << 2) + lq) << 3) ^ aswz);               \
        const f16x8 a0v = *(const f16x8*)&A[ak];                               \
        const f16x8 a1v = *(const f16x8*)&A[ak + 16 * 768];                    \
        _Pragma("unroll")                                                      \
        for (int nt = 0; nt < 4; ++nt) {                                       \
            ACC0[nt] = __builtin_amdgcn_mfma_f32_16x16x32_f16(a0v, wcur[nt], ACC0[nt], 0, 0, 0); \
            ACC1[nt] = __builtin_amdgcn_mfma_f32_16x16x32_f16(a1v, wcur[nt], ACC1[nt], 0, 0, 0); \
        }                                                                      \
        _Pragma("unroll")                                                      \
        for (int nt = 0; nt < 4; ++nt) wcur[nt] = wnxt[nt];                    \
    }                                                                          \
  }

__global__ __launch_bounds__(512, 2)
void qjrb_mfma(const float* __restrict__ x, const float* __restrict__ q,
               const f16* __restrict__ wsW,
               const float* __restrict__ b1, const float* __restrict__ b2,
               const float* __restrict__ b3, float* __restrict__ out)
{
    // A: [m][k] fp16, 16B-granule stored-slot = logical_granule ^ (m&7)
    __shared__ __align__(16) f16 A[MB * 768];   // 96 KiB

    const int tid = threadIdx.x;
    const int lan = tid & 63;
    const int wv  = tid >> 6;          // 0..7
    const int wr  = (wv >> 2) << 5;    // row offset: 0 or 32
    const int wc  = (wv & 3) << 6;     // col offset: 0,64,128,192
    const int lr  = lan & 15;          // A row-in-tile / D col-in-tile
    const int lq  = lan >> 4;          // k-quarter / D row-quad
    const int n0  = blockIdx.x * MB;

    // bias fragments (per-lane, reused across groups)
    float bf0[4], bf1[4], bf2[4];
    #pragma unroll
    for (int nt = 0; nt < 4; ++nt) {
        bf0[nt] = b1[wc + nt * 16 + lr];
        bf1[nt] = b2[wc + nt * 16 + lr];
        bf2[nt] = b3[wc + nt * 16 + lr];
    }

    const int wboff = lq * 2048 + (wc + lr) * 8;  // halves within a W tile
    const int abase = (wr + lr) * 768;            // halves
    const int aswz  = (lr & 7) << 3;              // halves XOR (16B-granule swizzle)

    f32x4 accO[3][2][4];   // layer-3 accumulators, one set per group (static idx)

    #pragma unroll
    for (int g = 0; g < 3; ++g) {
        __syncthreads();   // all reads of A (previous group) done
        // ---- stage A: x cols (2g,2g+1) -> k=2c{,+1}; q col g -> k=512+c
        {
            const int c  = tid & 255;
            const int rb = (tid >> 8) << 5;   // 0 or 32: row half
            const float* xp = x + ((size_t)(n0 + rb) * CH + c) * 6 + 2 * g;
            const float* qp = q + ((size_t)(n0 + rb) * CH + c) * 3 + g;
            #pragma unroll 8
            for (int r = 0; r < 32; ++r) {
                const float2 xx = *(const float2*)(xp + (size_t)r * (CH * 6));
                const float  qq = qp[(size_t)r * (CH * 3)];
                const int row = rb + r, sw = row & 7;
                f16x2 hx = { (f16)xx.x, (f16)xx.y };
                *(f16x2*)&A[row * 768 + (((c >> 2) ^ sw) << 3) + ((c & 3) << 1)] = hx;
                A[row * 768 + ((64 + ((c >> 3) ^ sw)) << 3) + (c & 7)] = (f16)qq;
            }
        }
        __syncthreads();   // A staged

        // ---- layers 1,2: barrier-free K-loop, relu back into A's q region
        #pragma unroll
        for (int l = 0; l < 2; ++l) {
            const f16* Wl = wsW + (size_t)l * NKT * 8192;
            f32x4 acc[2][4];
            #pragma unroll
            for (int nt = 0; nt < 4; ++nt) {
                const float bv = (l == 0) ? bf0[nt] : bf1[nt];
                acc[0][nt] = (f32x4){bv, bv, bv, bv};
                acc[1][nt] = (f32x4){bv, bv, bv, bv};
            }
            KLOOP(Wl, acc[0], acc[1]);
            __syncthreads();   // all waves done reading A before q-rewrite
            #pragma unroll
            for (int mt = 0; mt < 2; ++mt)
                #pragma unroll
                for (int i = 0; i < 4; ++i) {
                    const int m = wr + mt * 16 + lq * 4 + i;
                    const int sw = m & 7;
                    #pragma unroll
                    for (int nt = 0; nt < 4; ++nt) {
                        const int o = wc + nt * 16 + lr;
                        A[m * 768 + ((64 + ((o >> 3) ^ sw)) << 3) + (o & 7)] =
                            (f16)fmaxf(acc[mt][nt][i], 0.f);
                    }
                }
            __syncthreads();   // q published
        }

        // ---- layer 3 into accO[g] (held in registers until the fused epilogue)
        {
            const f16* Wl = wsW + (size_t)2 * NKT * 8192;
            #pragma unroll
            for (int nt = 0; nt < 4; ++nt) {
                const float bv = bf2[nt];
                accO[g][0][nt] = (f32x4){bv, bv, bv, bv};
                accO[g][1][nt] = (f32x4){bv, bv, bv, bv};
            }
            KLOOP(Wl, accO[g][0], accO[g][1]);
        }
    }

    // ---- fused epilogue: relu(acc + q_orig), all 3 g per (n,o) -> full 12B runs
    #pragma unroll
    for (int mt = 0; mt < 2; ++mt)
        #pragma unroll
        for (int i = 0; i < 4; ++i) {
            const int n = n0 + wr + mt * 16 + lq * 4 + i;
            #pragma unroll
            for (int nt = 0; nt < 4; ++nt) {
                const int o = wc + nt * 16 + lr;
                const size_t base = ((size_t)n * CH + o) * 3;
                #pragma unroll
                for (int g3 = 0; g3 < 3; ++g3)
                    out[base + g3] = fmaxf(accO[g3][mt][nt][i] + q[base + g3], 0.f);
            }
        }
}

extern "C" void kernel_launch(void* const* d_in, const int* in_sizes, int n_in,
                              void* d_out, int out_size, void* d_ws, size_t ws_size,
                              hipStream_t stream)
{
    const float* x  = (const float*)d_in[0];
    const float* q  = (const float*)d_in[1];
    const float* W1 = (const float*)d_in[2];
    const float* b1 = (const float*)d_in[3];
    const float* W2 = (const float*)d_in[4];
    const float* b2 = (const float*)d_in[5];
    const float* W3 = (const float*)d_in[6];
    const float* b3 = (const float*)d_in[7];

    if (ws_size < (size_t)3 * NKT * 16384) return;  // 1.13 MiB fp16 weight images
    f16* ws = (f16*)d_ws;

    hipLaunchKernelGGL(prep_w, dim3(3 * NKT), dim3(256), 0, stream, W1, W2, W3, ws);
    hipLaunchKernelGGL(qjrb_mfma, dim3(NR / MB), dim3(512), 0, stream,
                       x, q, ws, b1, b2, b3, (float*)d_out);
}